// Round 14
// baseline (66.670 us; speedup 1.0000x reference)
//
#include <hip/hip_runtime.h>
#include <hip/hip_bf16.h>
#include <stdint.h>

using bf = __bf16;
typedef __attribute__((ext_vector_type(8))) __bf16 bf16x8;
typedef __attribute__((ext_vector_type(4))) float f32x4;
typedef __attribute__((ext_vector_type(4))) int i32x4;

#define M_TOT 4096
#define D_EMB 512
#define F_FFN 2048

// ---------- async global->LDS, 16B per lane ----------
__device__ __forceinline__ void gload_lds16(const void* g, void* l) {
  __builtin_amdgcn_global_load_lds(
      (const __attribute__((address_space(1))) uint32_t*)g,
      (__attribute__((address_space(3))) uint32_t*)l, 16, 0, 0);
}

// ---------- 128B-row swizzled tiles ----------
__device__ __forceinline__ int swz128(int row, int b) {
  return row * 128 + (b ^ ((row & 7) << 4));
}
__device__ __forceinline__ bf16x8 ldf128(const char* base, int row, int b) {
  return *(const bf16x8*)(base + swz128(row, b));
}
__device__ __forceinline__ i32x4 ldf128i(const char* base, int row, int b) {
  return *(const i32x4*)(base + swz128(row, b));
}
// 4-wave stager: CHUNKS x 1KB (8 rows of 128B each); inverse-swizzled source
template <int CHUNKS>
__device__ __forceinline__ void stage_rows4(const void* gsrc, size_t ld_bytes, char* lbase,
                                            int wave, int lane) {
  const int rsub = lane >> 3, csub = lane & 7;
  const int sc = csub ^ rsub;
#pragma unroll
  for (int i = 0; i < CHUNKS / 4; ++i) {
    int chunk = wave + i * 4;
    int row = chunk * 8 + rsub;
    gload_lds16((const char*)gsrc + (size_t)row * ld_bytes + sc * 16, lbase + chunk * 1024);
  }
}
__device__ __forceinline__ int quant_i8(float x, float s) {
  float v = x * s;
  v = fminf(127.f, fmaxf(-127.f, v));
  return (int)rintf(v);
}

// ---------- merged prep + sgen (R13 body; x-read vectorized to float4) ----------
#define NB_SGEN 1024
#define NT_FT   2048
#define NT_W1   1024
#define NT_W2   1024

__global__ __launch_bounds__(256) void k_prep(const float* __restrict__ x,
                                              const float* __restrict__ W1,
                                              const float* __restrict__ W2,
                                              int8_t* __restrict__ fi8, bf* __restrict__ w1T,
                                              bf* __restrict__ w2T, int8_t* __restrict__ S) {
  __shared__ __align__(16) char smem[32768];
  const int bid = blockIdx.x, tid = threadIdx.x;

  if (bid < NB_SGEN) {
    char* phiL = smem;
    char* st = smem + 16384;
    // XCD-aligned S placement (R13): XCD e = bid&7 writes S rows [e*512,(e+1)*512)
    const int e = bid & 7, idx = bid >> 3;
    const int jt = e * 4 + (idx & 3);
    const int mt = idx >> 2;
    const int m0 = mt * 128;
    const int j0 = jt * 128;
    {
      int g = (tid < 128) ? (m0 + tid) : (j0 + tid - 128);
      f32x4 xv = *(const f32x4*)(x + (size_t)g * D_EMB);  // one 16B load
      float c[4], s[4];
#pragma unroll
      for (int k = 0; k < 4; ++k) sincosf(xv[k] * 0.5f, &s[k], &c[k]);
      bf* row = (bf*)(phiL + tid * 64);
#pragma unroll
      for (int m = 0; m < 16; ++m) {
        float p = 1.0f;
#pragma unroll
        for (int k = 0; k < 4; ++k) p *= ((m >> k) & 1) ? s[k] : c[k];
        row[m] = (bf)p;
      }
#pragma unroll
      for (int m = 16; m < 32; ++m) row[m] = (bf)0.0f;
    }
    __syncthreads();

    const int wave = tid >> 6, lane = tid & 63;
    const int lr = lane & 15, lg = lane >> 4;
    const bf16x8 a0 = *(const bf16x8*)(phiL + (wave * 32 + lr) * 64 + lg * 16);
    const bf16x8 a1 = *(const bf16x8*)(phiL + (wave * 32 + 16 + lr) * 64 + lg * 16);

    const int mb0 = wave * 32 + lg * 4;
    const int key = (lr & 7) << 4;
#pragma unroll
    for (int jf = 0; jf < 8; ++jf) {
      bf16x8 b = *(const bf16x8*)(phiL + (128 + jf * 16 + lr) * 64 + lg * 16);
      f32x4 s0 = __builtin_amdgcn_mfma_f32_16x16x32_bf16(a0, b, f32x4{0.f, 0.f, 0.f, 0.f}, 0, 0, 0);
      f32x4 s1 = __builtin_amdgcn_mfma_f32_16x16x32_bf16(a1, b, f32x4{0.f, 0.f, 0.f, 0.f}, 0, 0, 0);
      uint32_t w0 = 0, w1 = 0;
#pragma unroll
      for (int r = 0; r < 4; ++r) {
        uint32_t q0 = (uint32_t)min(127, (int)rintf(fabsf(s0[r]) * 127.f));
        uint32_t q1 = (uint32_t)min(127, (int)rintf(fabsf(s1[r]) * 127.f));
        w0 |= q0 << (8 * r);
        w1 |= q1 << (8 * r);
      }
      int jrow = jf * 16 + lr;
      *(uint32_t*)(st + jrow * 128 + (mb0 ^ key)) = w0;
      *(uint32_t*)(st + jrow * 128 + ((mb0 + 16) ^ key)) = w1;
    }
    __syncthreads();
#pragma unroll
    for (int i = 0; i < 4; ++i) {
      int idx2 = tid + i * 256;
      int jrow = idx2 >> 3, seg = idx2 & 7;
      i32x4 v = *(const i32x4*)(st + jrow * 128 + ((seg * 16) ^ ((jrow & 7) << 4)));
      *(i32x4*)(S + (size_t)(j0 + jrow) * M_TOT + m0 + seg * 16) = v;
    }
    return;
  }

  float(*tile)[33] = (float(*)[33])smem;
  const int tx = tid & 31, ty = tid >> 5;
  if (bid < NB_SGEN + NT_FT) {
    int b2 = bid - NB_SGEN;
    int c0 = (b2 % (D_EMB / 32)) * 32, r0 = (b2 / (D_EMB / 32)) * 32;
#pragma unroll
    for (int i = 0; i < 32; i += 8)
      tile[ty + i][tx] = x[(size_t)(r0 + ty + i) * D_EMB + c0 + tx];
    __syncthreads();
#pragma unroll
    for (int i = 0; i < 32; i += 8)
      fi8[(size_t)(c0 + ty + i) * M_TOT + r0 + tx] = (int8_t)quant_i8(tile[tx][ty + i], 15.875f);
  } else if (bid < NB_SGEN + NT_FT + NT_W1) {
    int b2 = bid - NB_SGEN - NT_FT;
    int c0 = (b2 % (F_FFN / 32)) * 32, r0 = (b2 / (F_FFN / 32)) * 32;
#pragma unroll
    for (int i = 0; i < 32; i += 8)
      tile[ty + i][tx] = W1[(size_t)(r0 + ty + i) * F_FFN + c0 + tx];
    __syncthreads();
#pragma unroll
    for (int i = 0; i < 32; i += 8)
      w1T[(size_t)(c0 + ty + i) * D_EMB + r0 + tx] = (bf)tile[tx][ty + i];
  } else {
    int b2 = bid - NB_SGEN - NT_FT - NT_W1;
    int c0 = (b2 % (D_EMB / 32)) * 32, r0 = (b2 / (D_EMB / 32)) * 32;
#pragma unroll
    for (int i = 0; i < 32; i += 8)
      tile[ty + i][tx] = W2[(size_t)(r0 + ty + i) * D_EMB + c0 + tx];
    __syncthreads();
#pragma unroll
    for (int i = 0; i < 32; i += 8)
      w2T[(size_t)(c0 + ty + i) * F_FFN + r0 + tx] = (bf)tile[tx][ty + i];
  }
}

// ---------- DEPTH-4 pipelined 4-wave BM64xBN64 GEMM (2 blocks/CU) ----------
// wait vmcnt(8): stages t+1,t+2 stay in flight; stage t+3 issued after barrier.
// Each stage gets ~3 iterations (~1500 cyc) of slack >= L3 latency.
template <int OUTMODE>
__global__ __launch_bounds__(256, 2) void k_g64(const bf* __restrict__ A, const bf* __restrict__ BT,
                                                const float* __restrict__ bias, void* __restrict__ out,
                                                int N, int K) {
  constexpr int BUF = 16384;
  __shared__ __align__(16) char sm[4 * BUF];  // 64KB

  const int tid = threadIdx.x;
  const int wave = tid >> 6, lane = tid & 63;
  const int lr = lane & 15, lg = lane >> 4;
  const int wm = wave & 1, wn = wave >> 1;

  const int lin = blockIdx.x;
  const int e = lin & 7, jj = lin >> 3;
  const int bm = e * 8 + (jj & 7), bn = jj >> 3;
  const int m0 = bm * 64, n0 = bn * 64;

  f32x4 acc[2][2];
#pragma unroll
  for (int i = 0; i < 2; ++i)
#pragma unroll
    for (int f = 0; f < 2; ++f) acc[i][f] = f32x4{0.f, 0.f, 0.f, 0.f};

  const size_t ldb = (size_t)K * 2;
  const int NT = K / 64;
  // prologue: stages 0,1,2
#pragma unroll
  for (int p = 0; p < 3; ++p) {
    stage_rows4<8>(A + (size_t)m0 * K + p * 64, ldb, sm + p * BUF, wave, lane);
    stage_rows4<8>(BT + (size_t)n0 * K + p * 64, ldb, sm + p * BUF + 8192, wave, lane);
  }

  for (int t = 0; t < NT; ++t) {
    char* aTc = sm + (t & 3) * BUF;
    char* bTc = aTc + 8192;
    if (t + 2 < NT)      asm volatile("s_waitcnt vmcnt(8)" ::: "memory");
    else if (t + 1 < NT) asm volatile("s_waitcnt vmcnt(4)" ::: "memory");
    else                 asm volatile("s_waitcnt vmcnt(0)" ::: "memory");
    __builtin_amdgcn_s_barrier();

    if (t + 3 < NT) {
      char* aTn = sm + ((t + 3) & 3) * BUF;
      stage_rows4<8>(A + (size_t)m0 * K + (t + 3) * 64, ldb, aTn, wave, lane);
      stage_rows4<8>(BT + (size_t)n0 * K + (t + 3) * 64, ldb, aTn + 8192, wave, lane);
    }
#pragma unroll
    for (int ksl = 0; ksl < 2; ++ksl) {
      bf16x8 a[2], b[2];
#pragma unroll
      for (int i = 0; i < 2; ++i) a[i] = ldf128(aTc, wm * 32 + i * 16 + lr, (ksl * 32 + lg * 8) * 2);
#pragma unroll
      for (int f = 0; f < 2; ++f) b[f] = ldf128(bTc, wn * 32 + f * 16 + lr, (ksl * 32 + lg * 8) * 2);
#pragma unroll
      for (int i = 0; i < 2; ++i)
#pragma unroll
        for (int f = 0; f < 2; ++f)
          acc[i][f] = __builtin_amdgcn_mfma_f32_16x16x32_bf16(a[i], b[f], acc[i][f], 0, 0, 0);
    }
  }

#pragma unroll
  for (int f = 0; f < 2; ++f) {
    int n = n0 + wn * 32 + f * 16 + lr;
    float bv = bias[n];
#pragma unroll
    for (int i = 0; i < 2; ++i)
#pragma unroll
      for (int r = 0; r < 4; ++r) {
        int m = m0 + wm * 32 + i * 16 + lg * 4 + r;
        float v = acc[i][f][r] + bv;
        if (OUTMODE == 1) {
          v = v > 0.f ? v : 0.f;
          ((bf*)out)[(size_t)m * N + n] = (bf)v;
        } else {
          ((float*)out)[(size_t)m * N + n] = v;
        }
      }
  }
}

// i8 variant, DEPTH-4: K-step 128 bytes, 4 waves = 2m x 2n, exact i32 acc
__global__ __launch_bounds__(256, 2) void k_gi64(const int8_t* __restrict__ S,
                                                 const int8_t* __restrict__ FT,
                                                 bf* __restrict__ outb) {
  constexpr int BUF = 16384;
  __shared__ __align__(16) char sm[4 * BUF];

  const int tid = threadIdx.x;
  const int wave = tid >> 6, lane = tid & 63;
  const int lr = lane & 15, lg = lane >> 4;
  const int wm = wave & 1, wn = wave >> 1;

  const int lin = blockIdx.x;
  const int e = lin & 7, jj = lin >> 3;
  const int bm = e * 8 + (jj & 7), bn = jj >> 3;
  const int m0 = bm * 64, n0 = bn * 64;

  i32x4 acc[2][2];
#pragma unroll
  for (int i = 0; i < 2; ++i)
#pragma unroll
    for (int f = 0; f < 2; ++f) acc[i][f] = i32x4{0, 0, 0, 0};

  constexpr int NT = M_TOT / 128;
#pragma unroll
  for (int p = 0; p < 3; ++p) {
    stage_rows4<8>(S + (size_t)m0 * M_TOT + p * 128, M_TOT, sm + p * BUF, wave, lane);
    stage_rows4<8>(FT + (size_t)n0 * M_TOT + p * 128, M_TOT, sm + p * BUF + 8192, wave, lane);
  }

  for (int t = 0; t < NT; ++t) {
    char* aTc = sm + (t & 3) * BUF;
    char* bTc = aTc + 8192;
    if (t + 2 < NT)      asm volatile("s_waitcnt vmcnt(8)" ::: "memory");
    else if (t + 1 < NT) asm volatile("s_waitcnt vmcnt(4)" ::: "memory");
    else                 asm volatile("s_waitcnt vmcnt(0)" ::: "memory");
    __builtin_amdgcn_s_barrier();

    if (t + 3 < NT) {
      char* aTn = sm + ((t + 3) & 3) * BUF;
      stage_rows4<8>(S + (size_t)m0 * M_TOT + (t + 3) * 128, M_TOT, aTn, wave, lane);
      stage_rows4<8>(FT + (size_t)n0 * M_TOT + (t + 3) * 128, M_TOT, aTn + 8192, wave, lane);
    }
#pragma unroll
    for (int ksub = 0; ksub < 2; ++ksub) {
      i32x4 a[2], b[2];
#pragma unroll
      for (int i = 0; i < 2; ++i) a[i] = ldf128i(aTc, wm * 32 + i * 16 + lr, ksub * 64 + lg * 16);
#pragma unroll
      for (int f = 0; f < 2; ++f) b[f] = ldf128i(bTc, wn * 32 + f * 16 + lr, ksub * 64 + lg * 16);
#pragma unroll
      for (int i = 0; i < 2; ++i)
#pragma unroll
        for (int f = 0; f < 2; ++f)
          acc[i][f] = __builtin_amdgcn_mfma_i32_16x16x64_i8(a[i], b[f], acc[i][f], 0, 0, 0);
    }
  }

  constexpr float SCALE = 8.0f / 16129.0f;
#pragma unroll
  for (int f = 0; f < 2; ++f) {
    int n = n0 + wn * 32 + f * 16 + lr;
#pragma unroll
    for (int i = 0; i < 2; ++i)
#pragma unroll
      for (int r = 0; r < 4; ++r) {
        int m = m0 + wm * 32 + i * 16 + lg * 4 + r;
        outb[(size_t)m * D_EMB + n] = (bf)((float)acc[i][f][r] * SCALE);
      }
  }
}

// ---------- workspace layout ----------
constexpr size_t OFF_FI8  = 0;
constexpr size_t OFF_OUTB = OFF_FI8 + (size_t)D_EMB * M_TOT;
constexpr size_t OFF_W1T  = OFF_OUTB + (size_t)M_TOT * D_EMB * 2;
constexpr size_t OFF_W2T  = OFF_W1T + (size_t)F_FFN * D_EMB * 2;
constexpr size_t OFF_S    = OFF_W2T + (size_t)D_EMB * F_FFN * 2;
constexpr size_t OFF_HB   = OFF_S;  // hb reuses S region (S dead before hb written)

extern "C" void kernel_launch(void* const* d_in, const int* in_sizes, int n_in,
                              void* d_out, int out_size, void* d_ws, size_t ws_size,
                              hipStream_t stream) {
  const float* x  = (const float*)d_in[0];
  const float* W1 = (const float*)d_in[1];
  const float* b1 = (const float*)d_in[2];
  const float* W2 = (const float*)d_in[3];
  const float* b2 = (const float*)d_in[4];
  float* y = (float*)d_out;
  char* ws = (char*)d_ws;

  int8_t* fi8 = (int8_t*)(ws + OFF_FI8);
  bf* outb    = (bf*)(ws + OFF_OUTB);
  bf* w1T     = (bf*)(ws + OFF_W1T);
  bf* w2T     = (bf*)(ws + OFF_W2T);
  int8_t* S   = (int8_t*)(ws + OFF_S);
  bf* hb      = (bf*)(ws + OFF_HB);

  k_prep<<<dim3(NB_SGEN + NT_FT + NT_W1 + NT_W2), 256, 0, stream>>>(x, W1, W2, fi8, w1T, w2T, S);

  // S @ flat : 512 blocks, m-panels XCD-matched to S writer
  k_gi64<<<dim3(512), 256, 0, stream>>>(S, fi8, outb);

  // FFN
  k_g64<1><<<dim3(2048), 256, 0, stream>>>(outb, w1T, b1, (void*)hb, F_FFN, D_EMB);
  k_g64<0><<<dim3(512), 256, 0, stream>>>(hb, w2T, b2, (void*)y, D_EMB, F_FFN);
}

// Round 15
// 63.199 us; speedup vs baseline: 1.0549x; 1.0549x over previous
//
#include <hip/hip_runtime.h>
#include <hip/hip_bf16.h>
#include <stdint.h>

using bf = __bf16;
typedef __attribute__((ext_vector_type(8))) __bf16 bf16x8;
typedef __attribute__((ext_vector_type(4))) __bf16 bf16x4;
typedef __attribute__((ext_vector_type(4))) float f32x4;
typedef __attribute__((ext_vector_type(4))) int i32x4;

#define M_TOT 4096
#define D_EMB 512
#define F_FFN 2048

// ---------- async global->LDS, 16B per lane ----------
__device__ __forceinline__ void gload_lds16(const void* g, void* l) {
  __builtin_amdgcn_global_load_lds(
      (const __attribute__((address_space(1))) uint32_t*)g,
      (__attribute__((address_space(3))) uint32_t*)l, 16, 0, 0);
}

// ---------- 128B-row swizzled tiles ----------
__device__ __forceinline__ int swz128(int row, int b) {
  return row * 128 + (b ^ ((row & 7) << 4));
}
__device__ __forceinline__ bf16x8 ldf128(const char* base, int row, int b) {
  return *(const bf16x8*)(base + swz128(row, b));
}
__device__ __forceinline__ i32x4 ldf128i(const char* base, int row, int b) {
  return *(const i32x4*)(base + swz128(row, b));
}
// 4-wave stager: CHUNKS x 1KB (8 rows of 128B each); inverse-swizzled source
template <int CHUNKS>
__device__ __forceinline__ void stage_rows4(const void* gsrc, size_t ld_bytes, char* lbase,
                                            int wave, int lane) {
  const int rsub = lane >> 3, csub = lane & 7;
  const int sc = csub ^ rsub;
#pragma unroll
  for (int i = 0; i < CHUNKS / 4; ++i) {
    int chunk = wave + i * 4;
    int row = chunk * 8 + rsub;
    gload_lds16((const char*)gsrc + (size_t)row * ld_bytes + sc * 16, lbase + chunk * 1024);
  }
}
__device__ __forceinline__ int quant_i8(float x, float s) {
  float v = x * s;
  v = fminf(127.f, fmaxf(-127.f, v));
  return (int)rintf(v);
}

// ---------- merged prep + sgen; store phases vectorized (4 cols / thread) ----------
#define NB_SGEN 1024
#define NT_FT   2048
#define NT_W1   1024
#define NT_W2   1024

__global__ __launch_bounds__(256) void k_prep(const float* __restrict__ x,
                                              const float* __restrict__ W1,
                                              const float* __restrict__ W2,
                                              int8_t* __restrict__ fi8, bf* __restrict__ w1T,
                                              bf* __restrict__ w2T, int8_t* __restrict__ S) {
  __shared__ __align__(16) char smem[32768];
  const int bid = blockIdx.x, tid = threadIdx.x;

  if (bid < NB_SGEN) {
    char* phiL = smem;
    char* st = smem + 16384;
    // XCD-aligned S placement (R13): XCD e = bid&7 writes S rows [e*512,(e+1)*512)
    const int e = bid & 7, idx = bid >> 3;
    const int jt = e * 4 + (idx & 3);
    const int mt = idx >> 2;
    const int m0 = mt * 128;
    const int j0 = jt * 128;
    {
      int g = (tid < 128) ? (m0 + tid) : (j0 + tid - 128);
      f32x4 xv = *(const f32x4*)(x + (size_t)g * D_EMB);  // one 16B load
      float c[4], s[4];
#pragma unroll
      for (int k = 0; k < 4; ++k) sincosf(xv[k] * 0.5f, &s[k], &c[k]);
      bf* row = (bf*)(phiL + tid * 64);
#pragma unroll
      for (int m = 0; m < 16; ++m) {
        float p = 1.0f;
#pragma unroll
        for (int k = 0; k < 4; ++k) p *= ((m >> k) & 1) ? s[k] : c[k];
        row[m] = (bf)p;
      }
#pragma unroll
      for (int m = 16; m < 32; ++m) row[m] = (bf)0.0f;
    }
    __syncthreads();

    const int wave = tid >> 6, lane = tid & 63;
    const int lr = lane & 15, lg = lane >> 4;
    const bf16x8 a0 = *(const bf16x8*)(phiL + (wave * 32 + lr) * 64 + lg * 16);
    const bf16x8 a1 = *(const bf16x8*)(phiL + (wave * 32 + 16 + lr) * 64 + lg * 16);

    const int mb0 = wave * 32 + lg * 4;
    const int key = (lr & 7) << 4;
#pragma unroll
    for (int jf = 0; jf < 8; ++jf) {
      bf16x8 b = *(const bf16x8*)(phiL + (128 + jf * 16 + lr) * 64 + lg * 16);
      f32x4 s0 = __builtin_amdgcn_mfma_f32_16x16x32_bf16(a0, b, f32x4{0.f, 0.f, 0.f, 0.f}, 0, 0, 0);
      f32x4 s1 = __builtin_amdgcn_mfma_f32_16x16x32_bf16(a1, b, f32x4{0.f, 0.f, 0.f, 0.f}, 0, 0, 0);
      uint32_t w0 = 0, w1 = 0;
#pragma unroll
      for (int r = 0; r < 4; ++r) {
        uint32_t q0 = (uint32_t)min(127, (int)rintf(fabsf(s0[r]) * 127.f));
        uint32_t q1 = (uint32_t)min(127, (int)rintf(fabsf(s1[r]) * 127.f));
        w0 |= q0 << (8 * r);
        w1 |= q1 << (8 * r);
      }
      int jrow = jf * 16 + lr;
      *(uint32_t*)(st + jrow * 128 + (mb0 ^ key)) = w0;
      *(uint32_t*)(st + jrow * 128 + ((mb0 + 16) ^ key)) = w1;
    }
    __syncthreads();
#pragma unroll
    for (int i = 0; i < 4; ++i) {
      int idx2 = tid + i * 256;
      int jrow = idx2 >> 3, seg = idx2 & 7;
      i32x4 v = *(const i32x4*)(st + jrow * 128 + ((seg * 16) ^ ((jrow & 7) << 4)));
      *(i32x4*)(S + (size_t)(j0 + jrow) * M_TOT + m0 + seg * 16) = v;
    }
    return;
  }

  float(*tile)[33] = (float(*)[33])smem;
  const int tx = tid & 31, ty = tid >> 5;
  const int cc = tid >> 3, g = tid & 7;  // store phase: row cc, col-group g (4 cols)
  if (bid < NB_SGEN + NT_FT) {
    // x (4096 x 512) -> fi8 [d][m], i8x4 stores
    int b2 = bid - NB_SGEN;
    int c0 = (b2 % (D_EMB / 32)) * 32, r0 = (b2 / (D_EMB / 32)) * 32;
#pragma unroll
    for (int i = 0; i < 32; i += 8)
      tile[ty + i][tx] = x[(size_t)(r0 + ty + i) * D_EMB + c0 + tx];
    __syncthreads();
    uint32_t pk = 0;
#pragma unroll
    for (int j = 0; j < 4; ++j)
      pk |= ((uint32_t)(uint8_t)(int8_t)quant_i8(tile[g * 4 + j][cc], 15.875f)) << (8 * j);
    *(uint32_t*)(fi8 + (size_t)(c0 + cc) * M_TOT + r0 + g * 4) = pk;
  } else if (bid < NB_SGEN + NT_FT + NT_W1) {
    // W1 (512 x 2048) -> w1T [f][d], bf16x4 stores
    int b2 = bid - NB_SGEN - NT_FT;
    int c0 = (b2 % (F_FFN / 32)) * 32, r0 = (b2 / (F_FFN / 32)) * 32;
#pragma unroll
    for (int i = 0; i < 32; i += 8)
      tile[ty + i][tx] = W1[(size_t)(r0 + ty + i) * F_FFN + c0 + tx];
    __syncthreads();
    bf16x4 pk;
#pragma unroll
    for (int j = 0; j < 4; ++j) pk[j] = (bf)tile[g * 4 + j][cc];
    *(bf16x4*)(w1T + (size_t)(c0 + cc) * D_EMB + r0 + g * 4) = pk;
  } else {
    // W2 (2048 x 512) -> w2T [d][f], bf16x4 stores
    int b2 = bid - NB_SGEN - NT_FT - NT_W1;
    int c0 = (b2 % (D_EMB / 32)) * 32, r0 = (b2 / (D_EMB / 32)) * 32;
#pragma unroll
    for (int i = 0; i < 32; i += 8)
      tile[ty + i][tx] = W2[(size_t)(r0 + ty + i) * D_EMB + c0 + tx];
    __syncthreads();
    bf16x4 pk;
#pragma unroll
    for (int j = 0; j < 4; ++j) pk[j] = (bf)tile[g * 4 + j][cc];
    *(bf16x4*)(w2T + (size_t)(c0 + cc) * F_FFN + r0 + g * 4) = pk;
  }
}

// ---------- R13 GEMMs: 4-wave BM64xBN64, 3-buffer, 3 blocks/CU ----------
template <int OUTMODE>
__global__ __launch_bounds__(256, 3) void k_g64(const bf* __restrict__ A, const bf* __restrict__ BT,
                                                const float* __restrict__ bias, void* __restrict__ out,
                                                int N, int K) {
  constexpr int BUF = 16384;
  __shared__ __align__(16) char sm[3 * BUF];

  const int tid = threadIdx.x;
  const int wave = tid >> 6, lane = tid & 63;
  const int lr = lane & 15, lg = lane >> 4;
  const int wm = wave & 1, wn = wave >> 1;

  const int lin = blockIdx.x;
  const int e = lin & 7, jj = lin >> 3;
  const int bm = e * 8 + (jj & 7), bn = jj >> 3;
  const int m0 = bm * 64, n0 = bn * 64;

  f32x4 acc[2][2];
#pragma unroll
  for (int i = 0; i < 2; ++i)
#pragma unroll
    for (int f = 0; f < 2; ++f) acc[i][f] = f32x4{0.f, 0.f, 0.f, 0.f};

  const size_t ldb = (size_t)K * 2;
  stage_rows4<8>(A + (size_t)m0 * K, ldb, sm, wave, lane);
  stage_rows4<8>(BT + (size_t)n0 * K, ldb, sm + 8192, wave, lane);
  stage_rows4<8>(A + (size_t)m0 * K + 64, ldb, sm + BUF, wave, lane);
  stage_rows4<8>(BT + (size_t)n0 * K + 64, ldb, sm + BUF + 8192, wave, lane);

  const int NT = K / 64;
  for (int t = 0; t < NT; ++t) {
    char* aTc = sm + (t % 3) * BUF;
    char* bTc = aTc + 8192;
    if (t + 1 < NT) asm volatile("s_waitcnt vmcnt(4)" ::: "memory");
    else            asm volatile("s_waitcnt vmcnt(0)" ::: "memory");
    __builtin_amdgcn_s_barrier();

    if (t + 2 < NT) {
      char* aTn = sm + ((t + 2) % 3) * BUF;
      stage_rows4<8>(A + (size_t)m0 * K + (t + 2) * 64, ldb, aTn, wave, lane);
      stage_rows4<8>(BT + (size_t)n0 * K + (t + 2) * 64, ldb, aTn + 8192, wave, lane);
    }
#pragma unroll
    for (int ksl = 0; ksl < 2; ++ksl) {
      bf16x8 a[2], b[2];
#pragma unroll
      for (int i = 0; i < 2; ++i) a[i] = ldf128(aTc, wm * 32 + i * 16 + lr, (ksl * 32 + lg * 8) * 2);
#pragma unroll
      for (int f = 0; f < 2; ++f) b[f] = ldf128(bTc, wn * 32 + f * 16 + lr, (ksl * 32 + lg * 8) * 2);
#pragma unroll
      for (int i = 0; i < 2; ++i)
#pragma unroll
        for (int f = 0; f < 2; ++f)
          acc[i][f] = __builtin_amdgcn_mfma_f32_16x16x32_bf16(a[i], b[f], acc[i][f], 0, 0, 0);
    }
  }

#pragma unroll
  for (int f = 0; f < 2; ++f) {
    int n = n0 + wn * 32 + f * 16 + lr;
    float bv = bias[n];
#pragma unroll
    for (int i = 0; i < 2; ++i)
#pragma unroll
      for (int r = 0; r < 4; ++r) {
        int m = m0 + wm * 32 + i * 16 + lg * 4 + r;
        float v = acc[i][f][r] + bv;
        if (OUTMODE == 1) {
          v = v > 0.f ? v : 0.f;
          ((bf*)out)[(size_t)m * N + n] = (bf)v;
        } else {
          ((float*)out)[(size_t)m * N + n] = v;
        }
      }
  }
}

// i8 variant (R13): K-step 128 bytes, 4 waves = 2m x 2n, exact i32 acc
__global__ __launch_bounds__(256, 3) void k_gi64(const int8_t* __restrict__ S,
                                                 const int8_t* __restrict__ FT,
                                                 bf* __restrict__ outb) {
  constexpr int BUF = 16384;
  __shared__ __align__(16) char sm[3 * BUF];

  const int tid = threadIdx.x;
  const int wave = tid >> 6, lane = tid & 63;
  const int lr = lane & 15, lg = lane >> 4;
  const int wm = wave & 1, wn = wave >> 1;

  const int lin = blockIdx.x;
  const int e = lin & 7, jj = lin >> 3;
  const int bm = e * 8 + (jj & 7), bn = jj >> 3;
  const int m0 = bm * 64, n0 = bn * 64;

  i32x4 acc[2][2];
#pragma unroll
  for (int i = 0; i < 2; ++i)
#pragma unroll
    for (int f = 0; f < 2; ++f) acc[i][f] = i32x4{0, 0, 0, 0};

  stage_rows4<8>(S + (size_t)m0 * M_TOT, M_TOT, sm, wave, lane);
  stage_rows4<8>(FT + (size_t)n0 * M_TOT, M_TOT, sm + 8192, wave, lane);
  stage_rows4<8>(S + (size_t)m0 * M_TOT + 128, M_TOT, sm + BUF, wave, lane);
  stage_rows4<8>(FT + (size_t)n0 * M_TOT + 128, M_TOT, sm + BUF + 8192, wave, lane);

  constexpr int NT = M_TOT / 128;
  for (int t = 0; t < NT; ++t) {
    char* aTc = sm + (t % 3) * BUF;
    char* bTc = aTc + 8192;
    if (t + 1 < NT) asm volatile("s_waitcnt vmcnt(4)" ::: "memory");
    else            asm volatile("s_waitcnt vmcnt(0)" ::: "memory");
    __builtin_amdgcn_s_barrier();

    if (t + 2 < NT) {
      char* aTn = sm + ((t + 2) % 3) * BUF;
      stage_rows4<8>(S + (size_t)m0 * M_TOT + (t + 2) * 128, M_TOT, aTn, wave, lane);
      stage_rows4<8>(FT + (size_t)n0 * M_TOT + (t + 2) * 128, M_TOT, aTn + 8192, wave, lane);
    }
#pragma unroll
    for (int ksub = 0; ksub < 2; ++ksub) {
      i32x4 a[2], b[2];
#pragma unroll
      for (int i = 0; i < 2; ++i) a[i] = ldf128i(aTc, wm * 32 + i * 16 + lr, ksub * 64 + lg * 16);
#pragma unroll
      for (int f = 0; f < 2; ++f) b[f] = ldf128i(bTc, wn * 32 + f * 16 + lr, ksub * 64 + lg * 16);
#pragma unroll
      for (int i = 0; i < 2; ++i)
#pragma unroll
        for (int f = 0; f < 2; ++f)
          acc[i][f] = __builtin_amdgcn_mfma_i32_16x16x64_i8(a[i], b[f], acc[i][f], 0, 0, 0);
    }
  }

  constexpr float SCALE = 8.0f / 16129.0f;
#pragma unroll
  for (int f = 0; f < 2; ++f) {
    int n = n0 + wn * 32 + f * 16 + lr;
#pragma unroll
    for (int i = 0; i < 2; ++i)
#pragma unroll
      for (int r = 0; r < 4; ++r) {
        int m = m0 + wm * 32 + i * 16 + lg * 4 + r;
        outb[(size_t)m * D_EMB + n] = (bf)((float)acc[i][f][r] * SCALE);
      }
  }
}

// ---------- workspace layout ----------
constexpr size_t OFF_FI8  = 0;
constexpr size_t OFF_OUTB = OFF_FI8 + (size_t)D_EMB * M_TOT;
constexpr size_t OFF_W1T  = OFF_OUTB + (size_t)M_TOT * D_EMB * 2;
constexpr size_t OFF_W2T  = OFF_W1T + (size_t)F_FFN * D_EMB * 2;
constexpr size_t OFF_S    = OFF_W2T + (size_t)D_EMB * F_FFN * 2;
constexpr size_t OFF_HB   = OFF_S;  // hb reuses S region (S dead before hb written)

extern "C" void kernel_launch(void* const* d_in, const int* in_sizes, int n_in,
                              void* d_out, int out_size, void* d_ws, size_t ws_size,
                              hipStream_t stream) {
  const float* x  = (const float*)d_in[0];
  const float* W1 = (const float*)d_in[1];
  const float* b1 = (const float*)d_in[2];
  const float* W2 = (const float*)d_in[3];
  const float* b2 = (const float*)d_in[4];
  float* y = (float*)d_out;
  char* ws = (char*)d_ws;

  int8_t* fi8 = (int8_t*)(ws + OFF_FI8);
  bf* outb    = (bf*)(ws + OFF_OUTB);
  bf* w1T     = (bf*)(ws + OFF_W1T);
  bf* w2T     = (bf*)(ws + OFF_W2T);
  int8_t* S   = (int8_t*)(ws + OFF_S);
  bf* hb      = (bf*)(ws + OFF_HB);

  k_prep<<<dim3(NB_SGEN + NT_FT + NT_W1 + NT_W2), 256, 0, stream>>>(x, W1, W2, fi8, w1T, w2T, S);

  // S @ flat : 512 blocks, m-panels XCD-matched to S writer
  k_gi64<<<dim3(512), 256, 0, stream>>>(S, fi8, outb);

  // FFN
  k_g64<1><<<dim3(2048), 256, 0, stream>>>(outb, w1T, b1, (void*)hb, F_FFN, D_EMB);
  k_g64<0><<<dim3(512), 256, 0, stream>>>(hb, w2T, b2, (void*)y, D_EMB, F_FFN);
}

// Round 16
// 61.945 us; speedup vs baseline: 1.0763x; 1.0202x over previous
//
#include <hip/hip_runtime.h>
#include <hip/hip_bf16.h>
#include <stdint.h>

using bf = __bf16;
typedef __attribute__((ext_vector_type(8))) __bf16 bf16x8;
typedef __attribute__((ext_vector_type(4))) __bf16 bf16x4;
typedef __attribute__((ext_vector_type(4))) float f32x4;
typedef __attribute__((ext_vector_type(4))) int i32x4;

#define M_TOT 4096
#define D_EMB 512
#define F_FFN 2048

// ---------- async global->LDS, 16B per lane ----------
__device__ __forceinline__ void gload_lds16(const void* g, void* l) {
  __builtin_amdgcn_global_load_lds(
      (const __attribute__((address_space(1))) uint32_t*)g,
      (__attribute__((address_space(3))) uint32_t*)l, 16, 0, 0);
}

// ---------- 128B-row swizzled tiles ----------
__device__ __forceinline__ int swz128(int row, int b) {
  return row * 128 + (b ^ ((row & 7) << 4));
}
__device__ __forceinline__ bf16x8 ldf128(const char* base, int row, int b) {
  return *(const bf16x8*)(base + swz128(row, b));
}
__device__ __forceinline__ i32x4 ldf128i(const char* base, int row, int b) {
  return *(const i32x4*)(base + swz128(row, b));
}
// 4-wave stager: CHUNKS x 1KB (8 rows of 128B each); inverse-swizzled source
template <int CHUNKS>
__device__ __forceinline__ void stage_rows4(const void* gsrc, size_t ld_bytes, char* lbase,
                                            int wave, int lane) {
  const int rsub = lane >> 3, csub = lane & 7;
  const int sc = csub ^ rsub;
#pragma unroll
  for (int i = 0; i < CHUNKS / 4; ++i) {
    int chunk = wave + i * 4;
    int row = chunk * 8 + rsub;
    gload_lds16((const char*)gsrc + (size_t)row * ld_bytes + sc * 16, lbase + chunk * 1024);
  }
}
__device__ __forceinline__ int quant_i8(float x, float s) {
  float v = x * s;
  v = fminf(127.f, fmaxf(-127.f, v));
  return (int)rintf(v);
}

// ---------- merged prep + sgen (R15, unchanged) ----------
#define NB_SGEN 1024
#define NT_FT   2048
#define NT_W1   1024
#define NT_W2   1024

__global__ __launch_bounds__(256) void k_prep(const float* __restrict__ x,
                                              const float* __restrict__ W1,
                                              const float* __restrict__ W2,
                                              int8_t* __restrict__ fi8, bf* __restrict__ w1T,
                                              bf* __restrict__ w2T, int8_t* __restrict__ S) {
  __shared__ __align__(16) char smem[32768];
  const int bid = blockIdx.x, tid = threadIdx.x;

  if (bid < NB_SGEN) {
    char* phiL = smem;
    char* st = smem + 16384;
    const int e = bid & 7, idx = bid >> 3;
    const int jt = e * 4 + (idx & 3);
    const int mt = idx >> 2;
    const int m0 = mt * 128;
    const int j0 = jt * 128;
    {
      int g = (tid < 128) ? (m0 + tid) : (j0 + tid - 128);
      f32x4 xv = *(const f32x4*)(x + (size_t)g * D_EMB);
      float c[4], s[4];
#pragma unroll
      for (int k = 0; k < 4; ++k) sincosf(xv[k] * 0.5f, &s[k], &c[k]);
      bf* row = (bf*)(phiL + tid * 64);
#pragma unroll
      for (int m = 0; m < 16; ++m) {
        float p = 1.0f;
#pragma unroll
        for (int k = 0; k < 4; ++k) p *= ((m >> k) & 1) ? s[k] : c[k];
        row[m] = (bf)p;
      }
#pragma unroll
      for (int m = 16; m < 32; ++m) row[m] = (bf)0.0f;
    }
    __syncthreads();

    const int wave = tid >> 6, lane = tid & 63;
    const int lr = lane & 15, lg = lane >> 4;
    const bf16x8 a0 = *(const bf16x8*)(phiL + (wave * 32 + lr) * 64 + lg * 16);
    const bf16x8 a1 = *(const bf16x8*)(phiL + (wave * 32 + 16 + lr) * 64 + lg * 16);

    const int mb0 = wave * 32 + lg * 4;
    const int key = (lr & 7) << 4;
#pragma unroll
    for (int jf = 0; jf < 8; ++jf) {
      bf16x8 b = *(const bf16x8*)(phiL + (128 + jf * 16 + lr) * 64 + lg * 16);
      f32x4 s0 = __builtin_amdgcn_mfma_f32_16x16x32_bf16(a0, b, f32x4{0.f, 0.f, 0.f, 0.f}, 0, 0, 0);
      f32x4 s1 = __builtin_amdgcn_mfma_f32_16x16x32_bf16(a1, b, f32x4{0.f, 0.f, 0.f, 0.f}, 0, 0, 0);
      uint32_t w0 = 0, w1 = 0;
#pragma unroll
      for (int r = 0; r < 4; ++r) {
        uint32_t q0 = (uint32_t)min(127, (int)rintf(fabsf(s0[r]) * 127.f));
        uint32_t q1 = (uint32_t)min(127, (int)rintf(fabsf(s1[r]) * 127.f));
        w0 |= q0 << (8 * r);
        w1 |= q1 << (8 * r);
      }
      int jrow = jf * 16 + lr;
      *(uint32_t*)(st + jrow * 128 + (mb0 ^ key)) = w0;
      *(uint32_t*)(st + jrow * 128 + ((mb0 + 16) ^ key)) = w1;
    }
    __syncthreads();
#pragma unroll
    for (int i = 0; i < 4; ++i) {
      int idx2 = tid + i * 256;
      int jrow = idx2 >> 3, seg = idx2 & 7;
      i32x4 v = *(const i32x4*)(st + jrow * 128 + ((seg * 16) ^ ((jrow & 7) << 4)));
      *(i32x4*)(S + (size_t)(j0 + jrow) * M_TOT + m0 + seg * 16) = v;
    }
    return;
  }

  float(*tile)[33] = (float(*)[33])smem;
  const int tx = tid & 31, ty = tid >> 5;
  const int cc = tid >> 3, g = tid & 7;
  if (bid < NB_SGEN + NT_FT) {
    int b2 = bid - NB_SGEN;
    int c0 = (b2 % (D_EMB / 32)) * 32, r0 = (b2 / (D_EMB / 32)) * 32;
#pragma unroll
    for (int i = 0; i < 32; i += 8)
      tile[ty + i][tx] = x[(size_t)(r0 + ty + i) * D_EMB + c0 + tx];
    __syncthreads();
    uint32_t pk = 0;
#pragma unroll
    for (int j = 0; j < 4; ++j)
      pk |= ((uint32_t)(uint8_t)(int8_t)quant_i8(tile[g * 4 + j][cc], 15.875f)) << (8 * j);
    *(uint32_t*)(fi8 + (size_t)(c0 + cc) * M_TOT + r0 + g * 4) = pk;
  } else if (bid < NB_SGEN + NT_FT + NT_W1) {
    int b2 = bid - NB_SGEN - NT_FT;
    int c0 = (b2 % (F_FFN / 32)) * 32, r0 = (b2 / (F_FFN / 32)) * 32;
#pragma unroll
    for (int i = 0; i < 32; i += 8)
      tile[ty + i][tx] = W1[(size_t)(r0 + ty + i) * F_FFN + c0 + tx];
    __syncthreads();
    bf16x4 pk;
#pragma unroll
    for (int j = 0; j < 4; ++j) pk[j] = (bf)tile[g * 4 + j][cc];
    *(bf16x4*)(w1T + (size_t)(c0 + cc) * D_EMB + r0 + g * 4) = pk;
  } else {
    int b2 = bid - NB_SGEN - NT_FT - NT_W1;
    int c0 = (b2 % (D_EMB / 32)) * 32, r0 = (b2 / (D_EMB / 32)) * 32;
#pragma unroll
    for (int i = 0; i < 32; i += 8)
      tile[ty + i][tx] = W2[(size_t)(r0 + ty + i) * D_EMB + c0 + tx];
    __syncthreads();
    bf16x4 pk;
#pragma unroll
    for (int j = 0; j < 4; ++j) pk[j] = (bf)tile[g * 4 + j][cc];
    *(bf16x4*)(w2T + (size_t)(c0 + cc) * F_FFN + r0 + g * 4) = pk;
  }
}

// ---------- R13 GEMM: 4-wave BM64xBN64, 3-buffer, 3 blocks/CU (gi64/gemm2) ----------
template <int OUTMODE>
__global__ __launch_bounds__(256, 3) void k_g64(const bf* __restrict__ A, const bf* __restrict__ BT,
                                                const float* __restrict__ bias, void* __restrict__ out,
                                                int N, int K) {
  constexpr int BUF = 16384;
  __shared__ __align__(16) char sm[3 * BUF];

  const int tid = threadIdx.x;
  const int wave = tid >> 6, lane = tid & 63;
  const int lr = lane & 15, lg = lane >> 4;
  const int wm = wave & 1, wn = wave >> 1;

  const int lin = blockIdx.x;
  const int e = lin & 7, jj = lin >> 3;
  const int bm = e * 8 + (jj & 7), bn = jj >> 3;
  const int m0 = bm * 64, n0 = bn * 64;

  f32x4 acc[2][2];
#pragma unroll
  for (int i = 0; i < 2; ++i)
#pragma unroll
    for (int f = 0; f < 2; ++f) acc[i][f] = f32x4{0.f, 0.f, 0.f, 0.f};

  const size_t ldb = (size_t)K * 2;
  stage_rows4<8>(A + (size_t)m0 * K, ldb, sm, wave, lane);
  stage_rows4<8>(BT + (size_t)n0 * K, ldb, sm + 8192, wave, lane);
  stage_rows4<8>(A + (size_t)m0 * K + 64, ldb, sm + BUF, wave, lane);
  stage_rows4<8>(BT + (size_t)n0 * K + 64, ldb, sm + BUF + 8192, wave, lane);

  const int NT = K / 64;
  for (int t = 0; t < NT; ++t) {
    char* aTc = sm + (t % 3) * BUF;
    char* bTc = aTc + 8192;
    if (t + 1 < NT) asm volatile("s_waitcnt vmcnt(4)" ::: "memory");
    else            asm volatile("s_waitcnt vmcnt(0)" ::: "memory");
    __builtin_amdgcn_s_barrier();

    if (t + 2 < NT) {
      char* aTn = sm + ((t + 2) % 3) * BUF;
      stage_rows4<8>(A + (size_t)m0 * K + (t + 2) * 64, ldb, aTn, wave, lane);
      stage_rows4<8>(BT + (size_t)n0 * K + (t + 2) * 64, ldb, aTn + 8192, wave, lane);
    }
#pragma unroll
    for (int ksl = 0; ksl < 2; ++ksl) {
      bf16x8 a[2], b[2];
#pragma unroll
      for (int i = 0; i < 2; ++i) a[i] = ldf128(aTc, wm * 32 + i * 16 + lr, (ksl * 32 + lg * 8) * 2);
#pragma unroll
      for (int f = 0; f < 2; ++f) b[f] = ldf128(bTc, wn * 32 + f * 16 + lr, (ksl * 32 + lg * 8) * 2);
#pragma unroll
      for (int i = 0; i < 2; ++i)
#pragma unroll
        for (int f = 0; f < 2; ++f)
          acc[i][f] = __builtin_amdgcn_mfma_f32_16x16x32_bf16(a[i], b[f], acc[i][f], 0, 0, 0);
    }
  }

#pragma unroll
  for (int f = 0; f < 2; ++f) {
    int n = n0 + wn * 32 + f * 16 + lr;
    float bv = bias[n];
#pragma unroll
    for (int i = 0; i < 2; ++i)
#pragma unroll
      for (int r = 0; r < 4; ++r) {
        int m = m0 + wm * 32 + i * 16 + lg * 4 + r;
        float v = acc[i][f][r] + bv;
        if (OUTMODE == 1) {
          v = v > 0.f ? v : 0.f;
          ((bf*)out)[(size_t)m * N + n] = (bf)v;
        } else {
          ((float*)out)[(size_t)m * N + n] = v;
        }
      }
  }
}

// ---------- gemm1 EXPERIMENT: 2-buffer/2-barrier, 32KB LDS -> 5 blocks/CU ----------
// Same tile/fragment/accumulation order as k_g64 (bit-identical results);
// only the buffering depth and occupancy change. 2048 blocks -> 20 waves/CU.
__global__ __launch_bounds__(256, 5) void k_g64b(const bf* __restrict__ A, const bf* __restrict__ BT,
                                                 const float* __restrict__ bias, bf* __restrict__ out,
                                                 int N, int K) {
  constexpr int BUF = 16384;
  __shared__ __align__(16) char sm[2 * BUF];  // 32KB

  const int tid = threadIdx.x;
  const int wave = tid >> 6, lane = tid & 63;
  const int lr = lane & 15, lg = lane >> 4;
  const int wm = wave & 1, wn = wave >> 1;

  const int lin = blockIdx.x;
  const int e = lin & 7, jj = lin >> 3;
  const int bm = e * 8 + (jj & 7), bn = jj >> 3;
  const int m0 = bm * 64, n0 = bn * 64;

  f32x4 acc[2][2];
#pragma unroll
  for (int i = 0; i < 2; ++i)
#pragma unroll
    for (int f = 0; f < 2; ++f) acc[i][f] = f32x4{0.f, 0.f, 0.f, 0.f};

  const size_t ldb = (size_t)K * 2;
  stage_rows4<8>(A + (size_t)m0 * K, ldb, sm, wave, lane);
  stage_rows4<8>(BT + (size_t)n0 * K, ldb, sm + 8192, wave, lane);
  stage_rows4<8>(A + (size_t)m0 * K + 64, ldb, sm + BUF, wave, lane);
  stage_rows4<8>(BT + (size_t)n0 * K + 64, ldb, sm + BUF + 8192, wave, lane);

  const int NT = K / 64;
  for (int t = 0; t < NT; ++t) {
    char* aTc = sm + (t & 1) * BUF;
    char* bTc = aTc + 8192;
    // stage(t) landed when only stage(t+1)'s 4 loads remain outstanding
    if (t + 1 < NT) asm volatile("s_waitcnt vmcnt(4)" ::: "memory");
    else            asm volatile("s_waitcnt vmcnt(0)" ::: "memory");
    __builtin_amdgcn_s_barrier();

#pragma unroll
    for (int ksl = 0; ksl < 2; ++ksl) {
      bf16x8 a[2], b[2];
#pragma unroll
      for (int i = 0; i < 2; ++i) a[i] = ldf128(aTc, wm * 32 + i * 16 + lr, (ksl * 32 + lg * 8) * 2);
#pragma unroll
      for (int f = 0; f < 2; ++f) b[f] = ldf128(bTc, wn * 32 + f * 16 + lr, (ksl * 32 + lg * 8) * 2);
#pragma unroll
      for (int i = 0; i < 2; ++i)
#pragma unroll
        for (int f = 0; f < 2; ++f)
          acc[i][f] = __builtin_amdgcn_mfma_f32_16x16x32_bf16(a[i], b[f], acc[i][f], 0, 0, 0);
    }
    __builtin_amdgcn_s_barrier();  // all waves done reading buf (t&1)
    if (t + 2 < NT) {              // refill the buffer just consumed
      char* aTn = sm + (t & 1) * BUF;
      stage_rows4<8>(A + (size_t)m0 * K + (t + 2) * 64, ldb, aTn, wave, lane);
      stage_rows4<8>(BT + (size_t)n0 * K + (t + 2) * 64, ldb, aTn + 8192, wave, lane);
    }
  }

#pragma unroll
  for (int f = 0; f < 2; ++f) {
    int n = n0 + wn * 32 + f * 16 + lr;
    float bv = bias[n];
#pragma unroll
    for (int i = 0; i < 2; ++i)
#pragma unroll
      for (int r = 0; r < 4; ++r) {
        int m = m0 + wm * 32 + i * 16 + lg * 4 + r;
        float v = acc[i][f][r] + bv;
        v = v > 0.f ? v : 0.f;
        out[(size_t)m * N + n] = (bf)v;
      }
  }
}

// i8 variant (R13, unchanged): K-step 128 bytes, 4 waves = 2m x 2n, exact i32 acc
__global__ __launch_bounds__(256, 3) void k_gi64(const int8_t* __restrict__ S,
                                                 const int8_t* __restrict__ FT,
                                                 bf* __restrict__ outb) {
  constexpr int BUF = 16384;
  __shared__ __align__(16) char sm[3 * BUF];

  const int tid = threadIdx.x;
  const int wave = tid >> 6, lane = tid & 63;
  const int lr = lane & 15, lg = lane >> 4;
  const int wm = wave & 1, wn = wave >> 1;

  const int lin = blockIdx.x;
  const int e = lin & 7, jj = lin >> 3;
  const int bm = e * 8 + (jj & 7), bn = jj >> 3;
  const int m0 = bm * 64, n0 = bn * 64;

  i32x4 acc[2][2];
#pragma unroll
  for (int i = 0; i < 2; ++i)
#pragma unroll
    for (int f = 0; f < 2; ++f) acc[i][f] = i32x4{0, 0, 0, 0};

  stage_rows4<8>(S + (size_t)m0 * M_TOT, M_TOT, sm, wave, lane);
  stage_rows4<8>(FT + (size_t)n0 * M_TOT, M_TOT, sm + 8192, wave, lane);
  stage_rows4<8>(S + (size_t)m0 * M_TOT + 128, M_TOT, sm + BUF, wave, lane);
  stage_rows4<8>(FT + (size_t)n0 * M_TOT + 128, M_TOT, sm + BUF + 8192, wave, lane);

  constexpr int NT = M_TOT / 128;
  for (int t = 0; t < NT; ++t) {
    char* aTc = sm + (t % 3) * BUF;
    char* bTc = aTc + 8192;
    if (t + 1 < NT) asm volatile("s_waitcnt vmcnt(4)" ::: "memory");
    else            asm volatile("s_waitcnt vmcnt(0)" ::: "memory");
    __builtin_amdgcn_s_barrier();

    if (t + 2 < NT) {
      char* aTn = sm + ((t + 2) % 3) * BUF;
      stage_rows4<8>(S + (size_t)m0 * M_TOT + (t + 2) * 128, M_TOT, aTn, wave, lane);
      stage_rows4<8>(FT + (size_t)n0 * M_TOT + (t + 2) * 128, M_TOT, aTn + 8192, wave, lane);
    }
#pragma unroll
    for (int ksub = 0; ksub < 2; ++ksub) {
      i32x4 a[2], b[2];
#pragma unroll
      for (int i = 0; i < 2; ++i) a[i] = ldf128i(aTc, wm * 32 + i * 16 + lr, ksub * 64 + lg * 16);
#pragma unroll
      for (int f = 0; f < 2; ++f) b[f] = ldf128i(bTc, wn * 32 + f * 16 + lr, ksub * 64 + lg * 16);
#pragma unroll
      for (int i = 0; i < 2; ++i)
#pragma unroll
        for (int f = 0; f < 2; ++f)
          acc[i][f] = __builtin_amdgcn_mfma_i32_16x16x64_i8(a[i], b[f], acc[i][f], 0, 0, 0);
    }
  }

  constexpr float SCALE = 8.0f / 16129.0f;
#pragma unroll
  for (int f = 0; f < 2; ++f) {
    int n = n0 + wn * 32 + f * 16 + lr;
#pragma unroll
    for (int i = 0; i < 2; ++i)
#pragma unroll
      for (int r = 0; r < 4; ++r) {
        int m = m0 + wm * 32 + i * 16 + lg * 4 + r;
        outb[(size_t)m * D_EMB + n] = (bf)((float)acc[i][f][r] * SCALE);
      }
  }
}

// ---------- workspace layout ----------
constexpr size_t OFF_FI8  = 0;
constexpr size_t OFF_OUTB = OFF_FI8 + (size_t)D_EMB * M_TOT;
constexpr size_t OFF_W1T  = OFF_OUTB + (size_t)M_TOT * D_EMB * 2;
constexpr size_t OFF_W2T  = OFF_W1T + (size_t)F_FFN * D_EMB * 2;
constexpr size_t OFF_S    = OFF_W2T + (size_t)D_EMB * F_FFN * 2;
constexpr size_t OFF_HB   = OFF_S;  // hb reuses S region (S dead before hb written)

extern "C" void kernel_launch(void* const* d_in, const int* in_sizes, int n_in,
                              void* d_out, int out_size, void* d_ws, size_t ws_size,
                              hipStream_t stream) {
  const float* x  = (const float*)d_in[0];
  const float* W1 = (const float*)d_in[1];
  const float* b1 = (const float*)d_in[2];
  const float* W2 = (const float*)d_in[3];
  const float* b2 = (const float*)d_in[4];
  float* y = (float*)d_out;
  char* ws = (char*)d_ws;

  int8_t* fi8 = (int8_t*)(ws + OFF_FI8);
  bf* outb    = (bf*)(ws + OFF_OUTB);
  bf* w1T     = (bf*)(ws + OFF_W1T);
  bf* w2T     = (bf*)(ws + OFF_W2T);
  int8_t* S   = (int8_t*)(ws + OFF_S);
  bf* hb      = (bf*)(ws + OFF_HB);

  k_prep<<<dim3(NB_SGEN + NT_FT + NT_W1 + NT_W2), 256, 0, stream>>>(x, W1, W2, fi8, w1T, w2T, S);

  // S @ flat : 512 blocks, m-panels XCD-matched to S writer (R13/R15 config)
  k_gi64<<<dim3(512), 256, 0, stream>>>(S, fi8, outb);

  // FFN: gemm1 = 2-buffer 5-blocks/CU experiment; gemm2 = R13 control
  k_g64b<<<dim3(2048), 256, 0, stream>>>(outb, w1T, b1, hb, F_FFN, D_EMB);
  k_g64<0><<<dim3(512), 256, 0, stream>>>(hb, w2T, b2, (void*)y, D_EMB, F_FFN);
}